// Round 3
// baseline (596.075 us; speedup 1.0000x reference)
//
#include <hip/hip_runtime.h>
#include <hip/hip_bf16.h>

// Problem: B=32, S=2048, D=1024, SIZE=1024
//   term1[b,s,k] = sum_d WO[k,d]*inputs[b,s,d]   (GEMM M=65536,N=1024,K=1024)
//   term2[b,k]   = sum_d WG[k,d]*g[b,d]
//   out[b,s]     = sum_k v[k]*tanh(term1+term2)
#define BB   32
#define SS   2048
#define DD   1024
#define SZ   1024
#define MM   (BB*SS)   // 65536

typedef short bf16x8 __attribute__((ext_vector_type(8)));
typedef float f32x4  __attribute__((ext_vector_type(4)));

__device__ __forceinline__ unsigned short f2bf(float x) {
    unsigned u = __float_as_uint(x);
    u += 0x7fffu + ((u >> 16) & 1u);      // RNE fp32->bf16 (finite normals)
    return (unsigned short)(u >> 16);
}
__device__ __forceinline__ unsigned pack2_bf16(float a, float b) {
    return (unsigned)f2bf(a) | ((unsigned)f2bf(b) << 16);
}
__device__ __forceinline__ float ftanh(float x) {
    float e = __expf(2.0f * x);
    return 1.0f - 2.0f / (e + 1.0f);
}

// ---------------- streaming converts (coalesced, 16B stores) ----------------
__global__ __launch_bounds__(256) void k_convA(const float* __restrict__ in,
                                               unsigned short* __restrict__ Abf) {
    size_t gid = (size_t)blockIdx.x * 256 + threadIdx.x;
    #pragma unroll
    for (int i = 0; i < 4; i++) {
        size_t base = (gid + (size_t)i * 8192 * 256) * 8;
        float4 w0 = *(const float4*)(in + base);
        float4 w1 = *(const float4*)(in + base + 4);
        uint4 o;
        o.x = pack2_bf16(w0.x, w0.y); o.y = pack2_bf16(w0.z, w0.w);
        o.z = pack2_bf16(w1.x, w1.y); o.w = pack2_bf16(w1.z, w1.w);
        *(uint4*)(Abf + base) = o;
    }
}

__global__ __launch_bounds__(256) void k_convWO(const float* __restrict__ WO,
                                                unsigned short* __restrict__ WOb) {
    size_t base = ((size_t)blockIdx.x * 256 + threadIdx.x) * 8;  // 512 blocks
    float4 w0 = *(const float4*)(WO + base);
    float4 w1 = *(const float4*)(WO + base + 4);
    uint4 o;
    o.x = pack2_bf16(w0.x, w0.y); o.y = pack2_bf16(w0.z, w0.w);
    o.z = pack2_bf16(w1.x, w1.y); o.w = pack2_bf16(w1.z, w1.w);
    *(uint4*)(WOb + base) = o;
}

// ---------------- term2 = WG @ g[b], coalesced (wave-per-k-row) -------------
// 256 blocks x 4 waves; wave handles row k = bid*4+wave for all 32 batches.
__global__ __launch_bounds__(256) void k_term2(const float* __restrict__ WG,
                                               const float* __restrict__ g,
                                               float* __restrict__ term2) {
    __shared__ float gs[32 * 512];   // 64 KB: g[:, c2*512 : +512]
    __shared__ float tmp[4][32];
    const int tid = threadIdx.x, wave = tid >> 6, lane = tid & 63;
    const int k = blockIdx.x * 4 + wave;
    float acc[32];
    #pragma unroll
    for (int b = 0; b < 32; b++) acc[b] = 0.f;

    for (int c2 = 0; c2 < 2; c2++) {
        #pragma unroll
        for (int i = 0; i < 16; i++) {
            int idx4 = i * 256 + tid;            // 4096 float4 total
            int flat = idx4 * 4;
            int b = flat >> 9, d = flat & 511;
            *(float4*)(gs + b * 512 + d) = *(const float4*)(g + (size_t)b * DD + c2 * 512 + d);
        }
        __syncthreads();
        #pragma unroll
        for (int sub = 0; sub < 2; sub++) {
            float4 wv = *(const float4*)(WG + (size_t)k * DD + c2 * 512 + sub * 256 + lane * 4);
            #pragma unroll
            for (int b = 0; b < 32; b++) {
                float4 g4 = *(const float4*)(gs + b * 512 + sub * 256 + lane * 4);
                acc[b] += wv.x * g4.x + wv.y * g4.y + wv.z * g4.z + wv.w * g4.w;
            }
        }
        __syncthreads();
    }
    #pragma unroll
    for (int b = 0; b < 32; b++) {
        float s = acc[b];
        s += __shfl_xor(s, 1);  s += __shfl_xor(s, 2);  s += __shfl_xor(s, 4);
        s += __shfl_xor(s, 8);  s += __shfl_xor(s, 16); s += __shfl_xor(s, 32);
        acc[b] = s;
    }
    if (lane == 0) {
        #pragma unroll
        for (int b = 0; b < 32; b++) tmp[wave][b] = acc[b];
    }
    __syncthreads();
    if (tid < 128) {
        int w = tid >> 5, b = tid & 31;
        term2[(size_t)b * SZ + blockIdx.x * 4 + w] = tmp[w][b];
    }
}

// ---------------- main GEMM (m97 structure) + tanh/v epilogue ---------------
// 128x128 tile, BK=32, 4 waves each 64x64 (4x4 of 16x16x32 bf16).
// Both tiles via global_load_lds(16B); chunk-XOR swizzle kills bank conflicts.
__global__ __launch_bounds__(256, 2) void k_gemm(
    const unsigned short* __restrict__ Abf,   // [MM, DD] bf16
    const unsigned short* __restrict__ WOb,   // [SZ, DD] bf16
    const float* __restrict__ term2,          // [BB, SZ]
    const float* __restrict__ v,              // [SZ]
    float* __restrict__ out) {                // [MM] (pre-zeroed)
    __shared__ unsigned short Asm[128 * 32];
    __shared__ unsigned short Bsm[128 * 32];
    __shared__ float part[2][128];

    const int tid = threadIdx.x, wave = tid >> 6, lane = tid & 63;
    const int wm = wave & 1, wn = wave >> 1;
    const int l15 = lane & 15, k8 = lane >> 4;
    const int bid = blockIdx.x;
    const int ntile = bid & 7, mtile = bid >> 3;  // 8 adjacent blocks share A-tile (LLC)
    const int m0 = mtile * 128, n0 = ntile * 128;
    const int bidx = m0 >> 11;                    // batch index
    const int sw = (l15 >> 1) & 3;                // frag-read swizzle (uniform/lane)

    f32x4 acc[4][4];
    #pragma unroll
    for (int i = 0; i < 4; i++)
        #pragma unroll
        for (int j = 0; j < 4; j++) acc[i][j] = (f32x4){0.f, 0.f, 0.f, 0.f};

    for (int k0 = 0; k0 < DD; k0 += 32) {
        #pragma unroll
        for (int r = 0; r < 2; r++) {
            int e = r * 256 + tid;                // chunk id 0..511 (16B chunks)
            int row = e >> 2, c = e & 3;
            int sc = c ^ ((row >> 1) & 3);        // source-chunk swizzle
            const unsigned short* srcA = Abf + (size_t)(m0 + row) * DD + k0 + sc * 8;
            __builtin_amdgcn_global_load_lds(
                (const __attribute__((address_space(1))) void*)srcA,
                (__attribute__((address_space(3))) void*)(&Asm[e * 8]), 16, 0, 0);
            const unsigned short* srcB = WOb + (size_t)(n0 + row) * DD + k0 + sc * 8;
            __builtin_amdgcn_global_load_lds(
                (const __attribute__((address_space(1))) void*)srcB,
                (__attribute__((address_space(3))) void*)(&Bsm[e * 8]), 16, 0, 0);
        }
        __syncthreads();

        bf16x8 af[4], bf[4];
        #pragma unroll
        for (int mi = 0; mi < 4; mi++)
            af[mi] = *(const bf16x8*)&Asm[(wm * 64 + mi * 16 + l15) * 32 + (k8 ^ sw) * 8];
        #pragma unroll
        for (int ni = 0; ni < 4; ni++)
            bf[ni] = *(const bf16x8*)&Bsm[(wn * 64 + ni * 16 + l15) * 32 + (k8 ^ sw) * 8];
        #pragma unroll
        for (int ni = 0; ni < 4; ni++)
            #pragma unroll
            for (int mi = 0; mi < 4; mi++)
                acc[mi][ni] = __builtin_amdgcn_mfma_f32_16x16x32_bf16(
                    af[mi], bf[ni], acc[mi][ni], 0, 0, 0);
        __syncthreads();
    }

    // epilogue: sum_n tanh(term1+term2)*v over this block's 128 n-columns
    float rsum[4][4];
    #pragma unroll
    for (int mi = 0; mi < 4; mi++)
        #pragma unroll
        for (int r = 0; r < 4; r++) rsum[mi][r] = 0.f;

    #pragma unroll
    for (int ni = 0; ni < 4; ni++) {
        int gn = n0 + wn * 64 + ni * 16 + l15;    // C/D: col = lane&15
        float t2 = term2[(size_t)bidx * SZ + gn];
        float vv = v[gn];
        #pragma unroll
        for (int mi = 0; mi < 4; mi++)
            #pragma unroll
            for (int r = 0; r < 4; r++)
                rsum[mi][r] += ftanh(acc[mi][ni][r] + t2) * vv;
    }
    #pragma unroll
    for (int mi = 0; mi < 4; mi++)
        #pragma unroll
        for (int r = 0; r < 4; r++) {
            float s = rsum[mi][r];
            s += __shfl_xor(s, 1, 16);
            s += __shfl_xor(s, 2, 16);
            s += __shfl_xor(s, 4, 16);
            s += __shfl_xor(s, 8, 16);
            rsum[mi][r] = s;
        }
    float val = 0.f;
    #pragma unroll
    for (int mi = 0; mi < 4; mi++)
        #pragma unroll
        for (int r = 0; r < 4; r++)
            if (l15 == mi * 4 + r) val = rsum[mi][r];
    {
        int mi = l15 >> 2, r = l15 & 3;           // row = wm*64+mi*16+k8*4+r
        part[wn][wm * 64 + mi * 16 + k8 * 4 + r] = val;
    }
    __syncthreads();
    if (tid < 128) atomicAdd(&out[m0 + tid], part[0][tid] + part[1][tid]);
}

// ---------------- fallback (ws too small): R2 fused kernel -----------------
__global__ __launch_bounds__(256, 2) void fused_main(
    const float* __restrict__ Ain, const unsigned short* __restrict__ WOb,
    const float* __restrict__ term2, const float* __restrict__ v,
    float* __restrict__ out) {
    __shared__ unsigned short Asm[128 * 40];
    __shared__ unsigned short Bsm[256 * 32];
    __shared__ float part[2][128];
    const int tid = threadIdx.x, wave = tid >> 6, lane = tid & 63;
    const int wm = wave & 1, wn = wave >> 1;
    const int l15 = lane & 15, k8 = lane >> 4;
    const int bid = blockIdx.x;
    const int ntile = bid & 3, mtile = bid >> 2;
    const int m0 = mtile * 128, n0 = ntile * 256;
    const int bidx = m0 >> 11;
    f32x4 acc[4][8];
    #pragma unroll
    for (int i = 0; i < 4; i++)
        #pragma unroll
        for (int j = 0; j < 8; j++) acc[i][j] = (f32x4){0.f, 0.f, 0.f, 0.f};
    for (int k0 = 0; k0 < DD; k0 += 32) {
        #pragma unroll
        for (int r = 0; r < 4; r++) {
            int chunk = r * 256 + tid;
            int n = chunk >> 2, ks = chunk & 3;
            const unsigned short* src = WOb + (size_t)(n0 + n) * DD + k0 + ks * 8;
            __builtin_amdgcn_global_load_lds(
                (const __attribute__((address_space(1))) void*)src,
                (__attribute__((address_space(3))) void*)(&Bsm[chunk * 8]), 16, 0, 0);
        }
        #pragma unroll
        for (int r = 0; r < 4; r++) {
            int e = r * 256 + tid;
            int row = e >> 3, qc = e & 7;
            float4 av = *(const float4*)(Ain + (size_t)(m0 + row) * DD + k0 + qc * 4);
            unsigned p0 = pack2_bf16(av.x, av.y), p1 = pack2_bf16(av.z, av.w);
            *(uint2*)&Asm[row * 40 + qc * 4] = make_uint2(p0, p1);
        }
        __syncthreads();
        bf16x8 afr[4], bfr[8];
        #pragma unroll
        for (int mi = 0; mi < 4; mi++)
            afr[mi] = *(const bf16x8*)&Asm[(wm * 64 + mi * 16 + l15) * 40 + k8 * 8];
        #pragma unroll
        for (int ni = 0; ni < 8; ni++)
            bfr[ni] = *(const bf16x8*)&Bsm[(wn * 128 + ni * 16 + l15) * 32 + k8 * 8];
        #pragma unroll
        for (int ni = 0; ni < 8; ni++)
            #pragma unroll
            for (int mi = 0; mi < 4; mi++)
                acc[mi][ni] = __builtin_amdgcn_mfma_f32_16x16x32_bf16(
                    afr[mi], bfr[ni], acc[mi][ni], 0, 0, 0);
        __syncthreads();
    }
    float rsum[4][4];
    #pragma unroll
    for (int mi = 0; mi < 4; mi++)
        #pragma unroll
        for (int r = 0; r < 4; r++) rsum[mi][r] = 0.f;
    #pragma unroll
    for (int ni = 0; ni < 8; ni++) {
        int gn = n0 + wn * 128 + ni * 16 + l15;
        float t2 = term2[(size_t)bidx * SZ + gn];
        float vv = v[gn];
        #pragma unroll
        for (int mi = 0; mi < 4; mi++)
            #pragma unroll
            for (int r = 0; r < 4; r++)
                rsum[mi][r] += ftanh(acc[mi][ni][r] + t2) * vv;
    }
    #pragma unroll
    for (int mi = 0; mi < 4; mi++)
        #pragma unroll
        for (int r = 0; r < 4; r++) {
            float s = rsum[mi][r];
            s += __shfl_xor(s, 1, 16); s += __shfl_xor(s, 2, 16);
            s += __shfl_xor(s, 4, 16); s += __shfl_xor(s, 8, 16);
            rsum[mi][r] = s;
        }
    float val = 0.f;
    #pragma unroll
    for (int mi = 0; mi < 4; mi++)
        #pragma unroll
        for (int r = 0; r < 4; r++)
            if (l15 == mi * 4 + r) val = rsum[mi][r];
    {
        int mi = l15 >> 2, r = l15 & 3;
        part[wn][wm * 64 + mi * 16 + k8 * 4 + r] = val;
    }
    __syncthreads();
    if (tid < 128) atomicAdd(&out[m0 + tid], part[0][tid] + part[1][tid]);
}

extern "C" void kernel_launch(void* const* d_in, const int* in_sizes, int n_in,
                              void* d_out, int out_size, void* d_ws, size_t ws_size,
                              hipStream_t stream) {
    const float* inputs = (const float*)d_in[0];   // [32,2048,1024]
    const float* g      = (const float*)d_in[1];   // [32,1024]
    const float* WO     = (const float*)d_in[2];   // [1024,1024]
    const float* WG     = (const float*)d_in[3];   // [1024,1024]
    const float* v      = (const float*)d_in[4];   // [1,1024]
    float* out = (float*)d_out;

    const size_t ABF_BYTES = (size_t)MM * DD * 2;          // 128 MB
    const size_t WOB_BYTES = (size_t)SZ * DD * 2;          // 2 MB
    const size_t T2_BYTES  = (size_t)BB * SZ * 4;          // 128 KB
    (void)hipMemsetAsync(d_out, 0, sizeof(float) * MM, stream);

    if (ws_size >= ABF_BYTES + WOB_BYTES + T2_BYTES) {
        unsigned short* Abf = (unsigned short*)d_ws;
        unsigned short* WOb = (unsigned short*)((char*)d_ws + ABF_BYTES);
        float* term2 = (float*)((char*)d_ws + ABF_BYTES + WOB_BYTES);
        k_convA<<<8192, 256, 0, stream>>>(inputs, Abf);
        k_convWO<<<512, 256, 0, stream>>>(WO, WOb);
        k_term2<<<256, 256, 0, stream>>>(WG, g, term2);
        k_gemm<<<(MM / 128) * (SZ / 128), 256, 0, stream>>>(Abf, WOb, term2, v, out);
    } else {
        unsigned short* WOb = (unsigned short*)d_ws;
        float* term2 = (float*)((char*)d_ws + WOB_BYTES);
        k_convWO<<<512, 256, 0, stream>>>(WO, WOb);
        k_term2<<<256, 256, 0, stream>>>(WG, g, term2);
        fused_main<<<(MM / 128) * (SZ / 256), 256, 0, stream>>>(inputs, WOb, term2, v, out);
    }
}

// Round 4
// 586.158 us; speedup vs baseline: 1.0169x; 1.0169x over previous
//
#include <hip/hip_runtime.h>
#include <hip/hip_bf16.h>

// Problem: B=32, S=2048, D=1024, SIZE=1024
//   term1[b,s,k] = sum_d WO[k,d]*inputs[b,s,d]   (GEMM M=65536,N=1024,K=1024)
//   term2[b,k]   = sum_d WG[k,d]*g[b,d]
//   out[b,s]     = sum_k v[k]*tanh(term1+term2)
// One-pass fused design: ws = 2.1 MB only (WOb + term2); A is converted
// fp32->bf16 in-register inside the GEMM K-loop (no 128MB intermediate,
// no big ws re-poison cost, no 384MB convert pass).
#define BB   32
#define SS   2048
#define DD   1024
#define SZ   1024
#define MM   (BB*SS)   // 65536

typedef short bf16x8 __attribute__((ext_vector_type(8)));
typedef float f32x4  __attribute__((ext_vector_type(4)));

__device__ __forceinline__ unsigned short f2bf(float x) {
    unsigned u = __float_as_uint(x);
    u += 0x7fffu + ((u >> 16) & 1u);      // RNE fp32->bf16 (finite normals)
    return (unsigned short)(u >> 16);
}
__device__ __forceinline__ unsigned pack2_bf16(float a, float b) {
    return (unsigned)f2bf(a) | ((unsigned)f2bf(b) << 16);
}
__device__ __forceinline__ float ftanh(float x) {
    float e = __expf(2.0f * x);
    return 1.0f - 2.0f / (e + 1.0f);
}

// ---------------- prep: WO->bf16 (bid<512) + term2 (bid>=512) ---------------
__global__ __launch_bounds__(256) void k_prep(const float* __restrict__ WO,
                                              const float* __restrict__ WG,
                                              const float* __restrict__ g,
                                              unsigned short* __restrict__ WOb,
                                              float* __restrict__ term2) {
    __shared__ float gs[32 * 512];   // 64 KB
    __shared__ float tmp[4][32];
    const int bid = blockIdx.x, tid = threadIdx.x;
    if (bid < 512) {
        size_t base = ((size_t)bid * 256 + tid) * 8;
        float4 w0 = *(const float4*)(WO + base);
        float4 w1 = *(const float4*)(WO + base + 4);
        uint4 o;
        o.x = pack2_bf16(w0.x, w0.y); o.y = pack2_bf16(w0.z, w0.w);
        o.z = pack2_bf16(w1.x, w1.y); o.w = pack2_bf16(w1.z, w1.w);
        *(uint4*)(WOb + base) = o;
        return;
    }
    // term2 = WG @ g[b], coalesced: wave handles row k for all 32 batches
    const int kb = bid - 512;            // 0..255
    const int wave = tid >> 6, lane = tid & 63;
    const int k = kb * 4 + wave;
    float acc[32];
    #pragma unroll
    for (int b = 0; b < 32; b++) acc[b] = 0.f;
    for (int c2 = 0; c2 < 2; c2++) {
        #pragma unroll
        for (int i = 0; i < 16; i++) {
            int idx4 = i * 256 + tid;
            int flat = idx4 * 4;
            int b = flat >> 9, d = flat & 511;
            *(float4*)(gs + b * 512 + d) = *(const float4*)(g + (size_t)b * DD + c2 * 512 + d);
        }
        __syncthreads();
        #pragma unroll
        for (int sub = 0; sub < 2; sub++) {
            float4 wv = *(const float4*)(WG + (size_t)k * DD + c2 * 512 + sub * 256 + lane * 4);
            #pragma unroll
            for (int b = 0; b < 32; b++) {
                float4 g4 = *(const float4*)(gs + b * 512 + sub * 256 + lane * 4);
                acc[b] += wv.x * g4.x + wv.y * g4.y + wv.z * g4.z + wv.w * g4.w;
            }
        }
        __syncthreads();
    }
    #pragma unroll
    for (int b = 0; b < 32; b++) {
        float s = acc[b];
        s += __shfl_xor(s, 1);  s += __shfl_xor(s, 2);  s += __shfl_xor(s, 4);
        s += __shfl_xor(s, 8);  s += __shfl_xor(s, 16); s += __shfl_xor(s, 32);
        acc[b] = s;
    }
    if (lane == 0) {
        #pragma unroll
        for (int b = 0; b < 32; b++) tmp[wave][b] = acc[b];
    }
    __syncthreads();
    if (tid < 128) {
        int w = tid >> 5, b = tid & 31;
        term2[(size_t)b * SZ + kb * 4 + w] = tmp[w][b];
    }
}

// ---------------- fused: GEMM(A fp32->bf16 in-loop) + tanh + v-reduce -------
// Block tile 64(M) x 256(N), BK=32. 4 waves; wave wn owns 64M x 64N (4x4 MFMA).
// B staged via global_load_lds(16B) with source-chunk XOR swizzle; A staged
// through VGPR (fp32 load + RNE pack) with the SAME swizzle -> conflict-free
// b128 frag reads (R3-measured: ~zero SQ_LDS_BANK_CONFLICT).
__global__ __launch_bounds__(256, 3) void fused_v2(
    const float* __restrict__ Ain,            // [MM, DD] fp32
    const unsigned short* __restrict__ WOb,   // [SZ, DD] bf16
    const float* __restrict__ term2,          // [BB, SZ]
    const float* __restrict__ v,              // [SZ]
    float* __restrict__ out) {                // [MM] (pre-zeroed)
    __shared__ unsigned short Asm[64 * 32];   // 4 KB
    __shared__ unsigned short Bsm[256 * 32];  // 16 KB
    __shared__ float part[4][64];             // 1 KB

    const int tid = threadIdx.x;
    const int wn  = tid >> 6;                 // wave = n-quarter
    const int lane = tid & 63;
    const int l15 = lane & 15, k8 = lane >> 4;
    const int sw  = (l15 >> 1) & 3;           // frag-read chunk swizzle

    const int bid = blockIdx.x;
    const int ntile = bid & 3, mtile = bid >> 2;  // 4 adjacent blocks share A rows (LLC)
    const int m0 = mtile * 64, n0 = ntile * 256;
    const int bidx = m0 >> 11;                // batch index (64-row tiles: 32 per batch)

    // A staging: thread -> (row, 8-k chunk), swizzled ds_write_b128
    const int rowA = tid >> 2, cA = tid & 3;
    const int scA = cA ^ ((rowA >> 1) & 3);
    const float* aptr = Ain + (size_t)(m0 + rowA) * DD + cA * 8;
    unsigned short* adst = &Asm[rowA * 32 + scA * 8];

    f32x4 acc[4][4];
    #pragma unroll
    for (int i = 0; i < 4; i++)
        #pragma unroll
        for (int j = 0; j < 4; j++) acc[i][j] = (f32x4){0.f, 0.f, 0.f, 0.f};

    for (int k0 = 0; k0 < DD; k0 += 32) {
        // B tile 256x32 bf16 = 1024 16B-chunks, 4 per thread, async to LDS
        #pragma unroll
        for (int r = 0; r < 4; r++) {
            int e = r * 256 + tid;
            int row = e >> 2, c = e & 3;
            int sc = c ^ ((row >> 1) & 3);
            const unsigned short* srcB = WOb + (size_t)(n0 + row) * DD + k0 + sc * 8;
            __builtin_amdgcn_global_load_lds(
                (const __attribute__((address_space(1))) void*)srcB,
                (__attribute__((address_space(3))) void*)(&Bsm[e * 8]), 16, 0, 0);
        }
        // A tile 64x32: 8 fp32 -> 8 bf16 per thread, one b128 store
        float4 a0 = *(const float4*)(aptr + k0);
        float4 a1 = *(const float4*)(aptr + k0 + 4);
        uint4 o;
        o.x = pack2_bf16(a0.x, a0.y); o.y = pack2_bf16(a0.z, a0.w);
        o.z = pack2_bf16(a1.x, a1.y); o.w = pack2_bf16(a1.z, a1.w);
        *(uint4*)adst = o;
        __syncthreads();

        bf16x8 af[4], bfr[4];
        #pragma unroll
        for (int mi = 0; mi < 4; mi++)
            af[mi] = *(const bf16x8*)&Asm[(mi * 16 + l15) * 32 + (k8 ^ sw) * 8];
        #pragma unroll
        for (int ni = 0; ni < 4; ni++)
            bfr[ni] = *(const bf16x8*)&Bsm[(wn * 64 + ni * 16 + l15) * 32 + (k8 ^ sw) * 8];
        #pragma unroll
        for (int ni = 0; ni < 4; ni++)
            #pragma unroll
            for (int mi = 0; mi < 4; mi++)
                acc[mi][ni] = __builtin_amdgcn_mfma_f32_16x16x32_bf16(
                    af[mi], bfr[ni], acc[mi][ni], 0, 0, 0);
        __syncthreads();
    }

    // epilogue: sum_n tanh(term1+term2)*v over this block's 256 n-columns
    float rsum[4][4];
    #pragma unroll
    for (int mi = 0; mi < 4; mi++)
        #pragma unroll
        for (int r = 0; r < 4; r++) rsum[mi][r] = 0.f;

    #pragma unroll
    for (int ni = 0; ni < 4; ni++) {
        int gn = n0 + wn * 64 + ni * 16 + l15;    // C/D: col = lane&15
        float t2 = term2[(size_t)bidx * SZ + gn];
        float vv = v[gn];
        #pragma unroll
        for (int mi = 0; mi < 4; mi++)
            #pragma unroll
            for (int r = 0; r < 4; r++)
                rsum[mi][r] += ftanh(acc[mi][ni][r] + t2) * vv;
    }
    #pragma unroll
    for (int mi = 0; mi < 4; mi++)
        #pragma unroll
        for (int r = 0; r < 4; r++) {
            float s = rsum[mi][r];
            s += __shfl_xor(s, 1, 16);
            s += __shfl_xor(s, 2, 16);
            s += __shfl_xor(s, 4, 16);
            s += __shfl_xor(s, 8, 16);
            rsum[mi][r] = s;
        }
    float val = 0.f;
    #pragma unroll
    for (int mi = 0; mi < 4; mi++)
        #pragma unroll
        for (int r = 0; r < 4; r++)
            if (l15 == mi * 4 + r) val = rsum[mi][r];
    {   // row within tile = mi*16 + k8*4 + r  (C/D: row = (lane>>4)*4 + reg)
        int mi = l15 >> 2, r = l15 & 3;
        part[wn][mi * 16 + k8 * 4 + r] = val;
    }
    __syncthreads();
    if (tid < 64)
        atomicAdd(&out[m0 + tid],
                  part[0][tid] + part[1][tid] + part[2][tid] + part[3][tid]);
}

extern "C" void kernel_launch(void* const* d_in, const int* in_sizes, int n_in,
                              void* d_out, int out_size, void* d_ws, size_t ws_size,
                              hipStream_t stream) {
    const float* inputs = (const float*)d_in[0];   // [32,2048,1024]
    const float* g      = (const float*)d_in[1];   // [32,1024]
    const float* WO     = (const float*)d_in[2];   // [1024,1024]
    const float* WG     = (const float*)d_in[3];   // [1024,1024]
    const float* v      = (const float*)d_in[4];   // [1,1024]
    float* out = (float*)d_out;

    unsigned short* WOb = (unsigned short*)d_ws;                    // 2 MB
    float* term2 = (float*)((char*)d_ws + (size_t)SZ * DD * 2);     // 128 KB

    (void)hipMemsetAsync(d_out, 0, sizeof(float) * MM, stream);
    k_prep<<<512 + 256, 256, 0, stream>>>(WO, WG, g, WOb, term2);
    fused_v2<<<(MM / 64) * (SZ / 256), 256, 0, stream>>>(inputs, WOb, term2, v, out);
}